// Round 1
// baseline (1262.589 us; speedup 1.0000x reference)
//
#include <hip/hip_runtime.h>
#include <hip/hip_bf16.h>

#define T_TOK 16384
#define HDIM  1024
#define FDIM  512
#define NEXP  64
#define NPAIR 32768   // T_TOK * K(=2)
#define BM    128
#define BK    64
#define MAXTILES 320  // <= NPAIR/BM + NEXP

typedef __attribute__((ext_vector_type(8))) short short8;
typedef __attribute__((ext_vector_type(4))) float f32x4;
typedef unsigned short ushort_t;

// ws int-layout:
// [0..63] counts | [64..127] cursors | [128..192] offsets(65) | [200] ntiles
// [256..575] tile_expert | [576..895] tile_rowstart
// [1024..33791] pair_token | then pair_coef (float, 32768)
// byte offset 1 MiB: act scratch, bf16 [NPAIR][FDIM]  (33.5 MiB)

__device__ __forceinline__ short f2bf(float f) {
  unsigned int u = __float_as_uint(f);
  u += 0x7FFFu + ((u >> 16) & 1u);   // round-to-nearest-even
  return (short)(u >> 16);
}

__device__ __forceinline__ short8 cvt8(float4 a, float4 b) {
  short8 v;
  v[0] = f2bf(a.x); v[1] = f2bf(a.y); v[2] = f2bf(a.z); v[3] = f2bf(a.w);
  v[4] = f2bf(b.x); v[5] = f2bf(b.y); v[6] = f2bf(b.z); v[7] = f2bf(b.w);
  return v;
}

__global__ void k_count(const int* __restrict__ ids, int* __restrict__ ws_i) {
  int i = blockIdx.x * 256 + threadIdx.x;
  if (i < NPAIR) atomicAdd(ws_i + ids[i], 1);
}

// one wave: prefix scans + tile list
__global__ void k_scan(int* __restrict__ ws_i) {
  int lane = threadIdx.x;   // 64 threads
  int cnt = ws_i[lane];
  int x = cnt;
  #pragma unroll
  for (int d = 1; d < 64; d <<= 1) {
    int y = __shfl_up(x, d, 64);
    if (lane >= d) x += y;
  }
  int excl = x - cnt;
  ws_i[128 + lane] = excl;
  if (lane == 63) ws_i[128 + 64] = x;

  int nt = (cnt + BM - 1) / BM;
  int tinc = nt;
  #pragma unroll
  for (int d = 1; d < 64; d <<= 1) {
    int y = __shfl_up(tinc, d, 64);
    if (lane >= d) tinc += y;
  }
  int texcl = tinc - nt;
  if (lane == 63) ws_i[200] = tinc;
  for (int i = 0; i < nt; i++) {
    ws_i[256 + texcl + i] = lane;          // expert id
    ws_i[576 + texcl + i] = excl + i * BM; // global row start
  }
}

__global__ void k_scatter(const int* __restrict__ ids, const float* __restrict__ wts,
                          int* __restrict__ ws_i) {
  int i = blockIdx.x * 256 + threadIdx.x;
  if (i < NPAIR) {
    int e = ids[i];
    int p = ws_i[128 + e] + atomicAdd(ws_i + 64 + e, 1);
    ws_i[1024 + p] = i >> 1;                               // token (K=2)
    ((float*)(ws_i + 1024 + NPAIR))[p] = wts[i];           // weight
  }
}

// ---------------- GEMM1: gu = gather(hs) @ w_gu^T ; act = silu(gate)*up ----
__global__ __launch_bounds__(256) void k_gemm1(
    const float* __restrict__ hs, const float* __restrict__ wgu,
    const int* __restrict__ ws_i, ushort_t* __restrict__ act) {
  int tile = blockIdx.x;
  if (tile >= ws_i[200]) return;
  int e       = ws_i[256 + tile];
  int row0    = ws_i[576 + tile];
  int row_end = ws_i[128 + e + 1];
  int nb      = blockIdx.y;              // 0..3, 128-col block of F
  const int* ptok = ws_i + 1024;

  __shared__ ushort_t sA[BM * BK], sBg[BM * BK], sBu[BM * BK];

  int tid = threadIdx.x, lane = tid & 63, wid = tid >> 6;
  int wm = wid >> 1, wn = wid & 1;

  f32x4 accg[4][4], accu[4][4];
  #pragma unroll
  for (int m = 0; m < 4; m++)
    #pragma unroll
    for (int n = 0; n < 4; n++) {
      accg[m][n] = (f32x4){0.f, 0.f, 0.f, 0.f};
      accu[m][n] = (f32x4){0.f, 0.f, 0.f, 0.f};
    }

  const float* wg_base = wgu + (size_t)e * (2 * FDIM * HDIM);

  int tokc[4];
  #pragma unroll
  for (int i = 0; i < 4; i++) {
    int c = tid + 256 * i;
    int row = c >> 3;
    int pos = row0 + row;
    tokc[i] = ptok[pos < NPAIR ? pos : NPAIR - 1];  // clamped: padding rows discarded later
  }

  for (int kt = 0; kt < HDIM / BK; ++kt) {
    int k0 = kt * BK;
    #pragma unroll
    for (int i = 0; i < 4; i++) {
      int c = tid + 256 * i;
      int row = c >> 3, scol = (c & 7) * 8;
      int sidx = row * 64 + (scol ^ ((row & 7) << 3));   // T2 XOR swizzle
      const float4* pa = reinterpret_cast<const float4*>(hs + (size_t)tokc[i] * HDIM + k0 + scol);
      *reinterpret_cast<short8*>(&sA[sidx]) = cvt8(pa[0], pa[1]);
      const float4* pg = reinterpret_cast<const float4*>(wg_base + (size_t)(nb * BM + row) * HDIM + k0 + scol);
      *reinterpret_cast<short8*>(&sBg[sidx]) = cvt8(pg[0], pg[1]);
      const float4* pu = reinterpret_cast<const float4*>(wg_base + (size_t)(FDIM + nb * BM + row) * HDIM + k0 + scol);
      *reinterpret_cast<short8*>(&sBu[sidx]) = cvt8(pu[0], pu[1]);
    }
    __syncthreads();
    #pragma unroll
    for (int kc = 0; kc < 2; kc++) {
      int col = kc * 32 + (lane >> 4) * 8;
      short8 af[4], gf[4], uf[4];
      #pragma unroll
      for (int m = 0; m < 4; m++) {
        int row = wm * 64 + m * 16 + (lane & 15);
        af[m] = *reinterpret_cast<const short8*>(&sA[row * 64 + (col ^ ((row & 7) << 3))]);
      }
      #pragma unroll
      for (int n = 0; n < 4; n++) {
        int row = wn * 64 + n * 16 + (lane & 15);
        int idx = row * 64 + (col ^ ((row & 7) << 3));
        gf[n] = *reinterpret_cast<const short8*>(&sBg[idx]);
        uf[n] = *reinterpret_cast<const short8*>(&sBu[idx]);
      }
      #pragma unroll
      for (int m = 0; m < 4; m++)
        #pragma unroll
        for (int n = 0; n < 4; n++) {
          accg[m][n] = __builtin_amdgcn_mfma_f32_16x16x32_bf16(af[m], gf[n], accg[m][n], 0, 0, 0);
          accu[m][n] = __builtin_amdgcn_mfma_f32_16x16x32_bf16(af[m], uf[n], accu[m][n], 0, 0, 0);
        }
    }
    __syncthreads();
  }
  // epilogue: act = silu(gate) * up, bf16
  #pragma unroll
  for (int m = 0; m < 4; m++)
    #pragma unroll
    for (int r = 0; r < 4; r++) {
      int row = wm * 64 + m * 16 + (lane >> 4) * 4 + r;
      int pos = row0 + row;
      if (pos < row_end) {
        #pragma unroll
        for (int n = 0; n < 4; n++) {
          int col = nb * 128 + wn * 64 + n * 16 + (lane & 15);
          float g = accg[m][n][r], u = accu[m][n][r];
          float s = g / (1.f + __expf(-g));
          act[(size_t)pos * FDIM + col] = (ushort_t)f2bf(s * u);
        }
      }
    }
}

// ---------------- GEMM2: y = act @ w_d^T ; out[token] += coef * y ----------
__global__ __launch_bounds__(256) void k_gemm2(
    const float* __restrict__ wd, const int* __restrict__ ws_i,
    const ushort_t* __restrict__ act, float* __restrict__ out) {
  int tile = blockIdx.x;
  if (tile >= ws_i[200]) return;
  int e       = ws_i[256 + tile];
  int row0    = ws_i[576 + tile];
  int row_end = ws_i[128 + e + 1];
  int nb      = blockIdx.y;              // 0..7, 128-col block of H
  const int* ptok = ws_i + 1024;
  const float* pcoef = (const float*)(ws_i + 1024 + NPAIR);

  __shared__ ushort_t sA[BM * BK], sB[BM * BK];

  int tid = threadIdx.x, lane = tid & 63, wid = tid >> 6;
  int wm = wid >> 1, wn = wid & 1;

  f32x4 acc[4][4];
  #pragma unroll
  for (int m = 0; m < 4; m++)
    #pragma unroll
    for (int n = 0; n < 4; n++) acc[m][n] = (f32x4){0.f, 0.f, 0.f, 0.f};

  const float* wd_base = wd + (size_t)e * HDIM * FDIM;

  for (int kt = 0; kt < FDIM / BK; ++kt) {
    int k0 = kt * BK;
    #pragma unroll
    for (int i = 0; i < 4; i++) {
      int c = tid + 256 * i;
      int row = c >> 3, scol = (c & 7) * 8;
      int sidx = row * 64 + (scol ^ ((row & 7) << 3));
      int pos = row0 + row; if (pos > NPAIR - 1) pos = NPAIR - 1;
      *reinterpret_cast<uint4*>(&sA[sidx]) =
          *reinterpret_cast<const uint4*>(act + (size_t)pos * FDIM + k0 + scol);
      const float4* pb = reinterpret_cast<const float4*>(wd_base + (size_t)(nb * BM + row) * FDIM + k0 + scol);
      *reinterpret_cast<short8*>(&sB[sidx]) = cvt8(pb[0], pb[1]);
    }
    __syncthreads();
    #pragma unroll
    for (int kc = 0; kc < 2; kc++) {
      int col = kc * 32 + (lane >> 4) * 8;
      short8 af[4], bf[4];
      #pragma unroll
      for (int m = 0; m < 4; m++) {
        int row = wm * 64 + m * 16 + (lane & 15);
        af[m] = *reinterpret_cast<const short8*>(&sA[row * 64 + (col ^ ((row & 7) << 3))]);
      }
      #pragma unroll
      for (int n = 0; n < 4; n++) {
        int row = wn * 64 + n * 16 + (lane & 15);
        bf[n] = *reinterpret_cast<const short8*>(&sB[row * 64 + (col ^ ((row & 7) << 3))]);
      }
      #pragma unroll
      for (int m = 0; m < 4; m++)
        #pragma unroll
        for (int n = 0; n < 4; n++)
          acc[m][n] = __builtin_amdgcn_mfma_f32_16x16x32_bf16(af[m], bf[n], acc[m][n], 0, 0, 0);
    }
    __syncthreads();
  }
  // epilogue: scatter-accumulate coef * y into out[token]
  #pragma unroll
  for (int m = 0; m < 4; m++)
    #pragma unroll
    for (int r = 0; r < 4; r++) {
      int row = wm * 64 + m * 16 + (lane >> 4) * 4 + r;
      int pos = row0 + row;
      if (pos < row_end) {
        int tok = ptok[pos];
        float coef = pcoef[pos];
        #pragma unroll
        for (int n = 0; n < 4; n++) {
          int col = nb * 128 + wn * 64 + n * 16 + (lane & 15);
          atomicAdd(out + (size_t)tok * HDIM + col, coef * acc[m][n][r]);
        }
      }
    }
}

extern "C" void kernel_launch(void* const* d_in, const int* in_sizes, int n_in,
                              void* d_out, int out_size, void* d_ws, size_t ws_size,
                              hipStream_t stream) {
  const float* hs  = (const float*)d_in[0];
  const float* tw  = (const float*)d_in[1];
  const int*   ids = (const int*)d_in[2];
  const float* wgu = (const float*)d_in[3];
  const float* wd  = (const float*)d_in[4];
  float* out = (float*)d_out;
  int* ws_i = (int*)d_ws;
  ushort_t* act = (ushort_t*)((char*)d_ws + (1u << 20));

  hipMemsetAsync(d_out, 0, (size_t)T_TOK * HDIM * sizeof(float), stream);
  hipMemsetAsync(d_ws, 0, 4096, stream);
  k_count<<<NPAIR / 256, 256, 0, stream>>>(ids, ws_i);
  k_scan<<<1, 64, 0, stream>>>(ws_i);
  k_scatter<<<NPAIR / 256, 256, 0, stream>>>(ids, tw, ws_i);
  k_gemm1<<<dim3(MAXTILES, 4), 256, 0, stream>>>(hs, wgu, ws_i, act);
  k_gemm2<<<dim3(MAXTILES, 8), 256, 0, stream>>>(wd, ws_i, act, out);
}